// Round 2
// baseline (1010.809 us; speedup 1.0000x reference)
//
#include <hip/hip_runtime.h>

// GraphAttention: N=12288, IN=OUT=128.
// e_new = emb@W.T ; s = e_new@a1 ; t = e_new@a2
// e[i][j] = leaky(s_i + t_j) masked by adj; softmax rows; out = relu(att @ e_new)
//
//  k1: bf16 MFMA gemm emb@W.T -> Vt (bf16, transposed [d][j]), s[], t[] (fp32)
//  ktmax: Tmax = max_j t_j (fixed per-row softmax shift; softmax partials add)
//  k2: streaming masked-softmax-PV, adj read once coalesced-ish int4,
//      P built directly in MFMA A-layout. 16 col-splits, partials to ws
//      (plain stores, no atomics). Register prefetch of next iter's adj/t.
//  kl: combine 16 softmax-denominator partials -> 1/l per row
//  k3: out = relu( (sum of 16 partials) * linv )

#define NN 12288
#define DIM 128
#define CSPLIT 16
#define COLS_PER (NN / CSPLIT)  // 768

typedef __bf16 bf16x8 __attribute__((ext_vector_type(8)));
typedef float f32x4 __attribute__((ext_vector_type(4)));

// ---------------- kernel 1: e_new = emb @ W.T (bf16 MFMA), emits Vt, s, t ----
__global__ __launch_bounds__(256) void k1_gemm(const float* __restrict__ emb,
                                               const float* __restrict__ W,
                                               const float* __restrict__ a,
                                               __bf16* __restrict__ Vt,
                                               float* __restrict__ s,
                                               float* __restrict__ t) {
  const int lane = threadIdx.x & 63;
  const int wave = threadIdx.x >> 6;
  const int m = lane & 15;
  const int quad = lane >> 4;
  const int row0 = blockIdx.x * 64 + wave * 16;  // this wave: 16 rows

  f32x4 acc[8];
#pragma unroll
  for (int nb = 0; nb < 8; nb++) acc[nb] = (f32x4){0.f, 0.f, 0.f, 0.f};

#pragma unroll
  for (int ks = 0; ks < 4; ks++) {
    const int k0 = ks * 32 + quad * 8;
    const float* ep = emb + (size_t)(row0 + m) * DIM + k0;
    float4 lo = *(const float4*)ep;
    float4 hi = *(const float4*)(ep + 4);
    bf16x8 af = {(__bf16)lo.x, (__bf16)lo.y, (__bf16)lo.z, (__bf16)lo.w,
                 (__bf16)hi.x, (__bf16)hi.y, (__bf16)hi.z, (__bf16)hi.w};
#pragma unroll
    for (int nb = 0; nb < 8; nb++) {
      const float* wp = W + (size_t)(nb * 16 + m) * DIM + k0;
      float4 wlo = *(const float4*)wp;
      float4 whi = *(const float4*)(wp + 4);
      bf16x8 bf = {(__bf16)wlo.x, (__bf16)wlo.y, (__bf16)wlo.z, (__bf16)wlo.w,
                   (__bf16)whi.x, (__bf16)whi.y, (__bf16)whi.z, (__bf16)whi.w};
      acc[nb] = __builtin_amdgcn_mfma_f32_16x16x32_bf16(af, bf, acc[nb], 0, 0, 0);
    }
  }

  float a1v[8], a2v[8];
#pragma unroll
  for (int nb = 0; nb < 8; nb++) {
    a1v[nb] = a[nb * 16 + m];
    a2v[nb] = a[DIM + nb * 16 + m];
  }
  // C/D layout: row = quad*4 + r, col = nb*16 + m
#pragma unroll
  for (int r = 0; r < 4; r++) {
    const int gr = row0 + quad * 4 + r;
    float ps = 0.f, pt = 0.f;
#pragma unroll
    for (int nb = 0; nb < 8; nb++) {
      float e = acc[nb][r];
      ps += e * a1v[nb];
      pt += e * a2v[nb];
      Vt[(size_t)(nb * 16 + m) * NN + gr] = (__bf16)e;
    }
    ps += __shfl_xor(ps, 1); ps += __shfl_xor(ps, 2);
    ps += __shfl_xor(ps, 4); ps += __shfl_xor(ps, 8);
    pt += __shfl_xor(pt, 1); pt += __shfl_xor(pt, 2);
    pt += __shfl_xor(pt, 4); pt += __shfl_xor(pt, 8);
    if (m == 0) { s[gr] = ps; t[gr] = pt; }
  }
}

// ---------------- kernel: Tmax = max(t) ------------------------------------
__global__ __launch_bounds__(256) void ktmax(const float* __restrict__ t,
                                             float* __restrict__ tmax) {
  __shared__ float red[256];
  float mx = -1e30f;
  for (int i = threadIdx.x; i < NN; i += 256) mx = fmaxf(mx, t[i]);
  red[threadIdx.x] = mx;
  __syncthreads();
  for (int off = 128; off; off >>= 1) {
    if ((int)threadIdx.x < off) red[threadIdx.x] = fmaxf(red[threadIdx.x], red[threadIdx.x + off]);
    __syncthreads();
  }
  if (threadIdx.x == 0) *tmax = red[0];
}

// ---------------- kernel 2: masked softmax + PV, streaming adj ---------------
__global__ __launch_bounds__(256, 3) void k2_attn(const int* __restrict__ adj,
                                                  const __bf16* __restrict__ Vt,
                                                  const float* __restrict__ s,
                                                  const float* __restrict__ t,
                                                  const float* __restrict__ tmaxp,
                                                  float* __restrict__ part,
                                                  float* __restrict__ lpart) {
  const int lane = threadIdx.x & 63;
  const int wave = threadIdx.x >> 6;
  const int m = lane & 15;
  const int quad = lane >> 4;
  const int row0 = blockIdx.x * 128 + wave * 32;
  const int cs = blockIdx.y;
  const int col0 = cs * COLS_PER;
  const int rowA = row0 + m;
  const int rowB = rowA + 16;

  const float Tmax = *tmaxp;
  const float sA = s[rowA], sB = s[rowB];
  const float uA = sA + Tmax, uB = sB + Tmax;
  const float mA = fmaxf(uA, 0.01f * uA);  // per-row fixed softmax shift (upper bound)
  const float mB = fmaxf(uB, 0.01f * uB);

  const int* adjA = adj + (size_t)rowA * NN + col0 + quad * 8;
  const int* adjB = adj + (size_t)rowB * NN + col0 + quad * 8;
  const float* tp = t + col0 + quad * 8;
  const __bf16* vp = Vt + (size_t)m * NN + col0 + quad * 8;

  f32x4 accA[8], accB[8];
#pragma unroll
  for (int nb = 0; nb < 8; nb++) {
    accA[nb] = (f32x4){0.f, 0.f, 0.f, 0.f};
    accB[nb] = (f32x4){0.f, 0.f, 0.f, 0.f};
  }
  float lA = 0.f, lB = 0.f;

  const int iters = COLS_PER / 32;  // 24
  // current-iteration data (prefetched)
  int4 cA0 = *(const int4*)(adjA);
  int4 cA1 = *(const int4*)(adjA + 4);
  int4 cB0 = *(const int4*)(adjB);
  int4 cB1 = *(const int4*)(adjB + 4);
  float4 ct0 = *(const float4*)(tp);
  float4 ct1 = *(const float4*)(tp + 4);

  for (int it = 0; it < iters; ++it) {
    const int kb = it * 32;
    const int nkb = (it + 1 < iters) ? kb + 32 : kb;  // last iter: harmless re-read
    // prefetch next iteration's HBM-latency data
    int4 nA0 = *(const int4*)(adjA + nkb);
    int4 nA1 = *(const int4*)(adjA + nkb + 4);
    int4 nB0 = *(const int4*)(adjB + nkb);
    int4 nB1 = *(const int4*)(adjB + nkb + 4);
    float4 nt0 = *(const float4*)(tp + nkb);
    float4 nt1 = *(const float4*)(tp + nkb + 4);

    bf16x8 bv[8];
#pragma unroll
    for (int nb = 0; nb < 8; nb++)
      bv[nb] = *(const bf16x8*)(vp + (size_t)nb * 16 * NN + kb);

    bf16x8 pA, pB;
#define PEL(frag, jj, tv, av, ss, mm, ll)                               \
    {                                                                   \
      float v = (ss) + (tv);                                            \
      float lv = fmaxf(v, 0.01f * v);                                   \
      float e = ((av) != 0) ? __expf(lv - (mm)) : 0.f;                  \
      (ll) += e;                                                        \
      frag[jj] = (__bf16)e;                                             \
    }
    PEL(pA, 0, ct0.x, cA0.x, sA, mA, lA)
    PEL(pA, 1, ct0.y, cA0.y, sA, mA, lA)
    PEL(pA, 2, ct0.z, cA0.z, sA, mA, lA)
    PEL(pA, 3, ct0.w, cA0.w, sA, mA, lA)
    PEL(pA, 4, ct1.x, cA1.x, sA, mA, lA)
    PEL(pA, 5, ct1.y, cA1.y, sA, mA, lA)
    PEL(pA, 6, ct1.z, cA1.z, sA, mA, lA)
    PEL(pA, 7, ct1.w, cA1.w, sA, mA, lA)
    PEL(pB, 0, ct0.x, cB0.x, sB, mB, lB)
    PEL(pB, 1, ct0.y, cB0.y, sB, mB, lB)
    PEL(pB, 2, ct0.z, cB0.z, sB, mB, lB)
    PEL(pB, 3, ct0.w, cB0.w, sB, mB, lB)
    PEL(pB, 4, ct1.x, cB1.x, sB, mB, lB)
    PEL(pB, 5, ct1.y, cB1.y, sB, mB, lB)
    PEL(pB, 6, ct1.z, cB1.z, sB, mB, lB)
    PEL(pB, 7, ct1.w, cB1.w, sB, mB, lB)
#undef PEL

#pragma unroll
    for (int nb = 0; nb < 8; nb++) {
      accA[nb] = __builtin_amdgcn_mfma_f32_16x16x32_bf16(pA, bv[nb], accA[nb], 0, 0, 0);
      accB[nb] = __builtin_amdgcn_mfma_f32_16x16x32_bf16(pB, bv[nb], accB[nb], 0, 0, 0);
    }

    cA0 = nA0; cA1 = nA1; cB0 = nB0; cB1 = nB1;
    ct0 = nt0; ct1 = nt1;
  }

  // row-sum partials: lanes {m, m+16, m+32, m+48} hold same row
  lA += __shfl_xor(lA, 16); lA += __shfl_xor(lA, 32);
  lB += __shfl_xor(lB, 16); lB += __shfl_xor(lB, 32);
  if (quad == 0) {
    lpart[(size_t)cs * NN + rowA] = lA;
    lpart[(size_t)cs * NN + rowB] = lB;
  }

  // C/D layout: row = quad*4 + r, col = nb*16 + m. Plain stores to partial slice.
  float* po = part + ((size_t)cs * NN + row0) * DIM;
#pragma unroll
  for (int nb = 0; nb < 8; nb++) {
#pragma unroll
    for (int r = 0; r < 4; r++) {
      po[(size_t)(quad * 4 + r) * DIM + nb * 16 + m] = accA[nb][r];
      po[(size_t)(16 + quad * 4 + r) * DIM + nb * 16 + m] = accB[nb][r];
    }
  }
}

// ---------------- kernel: combine denominator partials ----------------------
__global__ __launch_bounds__(256) void kl(const float* __restrict__ lpart,
                                          float* __restrict__ linv) {
  const int r = blockIdx.x * 256 + threadIdx.x;  // 48 blocks
  float l = 0.f;
#pragma unroll
  for (int cs = 0; cs < CSPLIT; cs++) l += lpart[(size_t)cs * NN + r];
  linv[r] = 1.0f / l;
}

// ---------------- kernel 3: reduce partials + normalize + relu ---------------
__global__ __launch_bounds__(256) void k3_fin(const float* __restrict__ part,
                                              const float* __restrict__ linv,
                                              float* __restrict__ out) {
  const int idx = blockIdx.x * 256 + threadIdx.x;  // over NN*DIM/4
  const int row = idx >> 5;                        // DIM/4 = 32 float4 per row
  const float4* p4 = (const float4*)part;
  float4 acc = p4[idx];
#pragma unroll
  for (int cs = 1; cs < CSPLIT; cs++) {
    float4 v = p4[(size_t)cs * (NN * DIM / 4) + idx];
    acc.x += v.x; acc.y += v.y; acc.z += v.z; acc.w += v.w;
  }
  const float li = linv[row];
  float4 o;
  o.x = fmaxf(acc.x * li, 0.f);
  o.y = fmaxf(acc.y * li, 0.f);
  o.z = fmaxf(acc.z * li, 0.f);
  o.w = fmaxf(acc.w * li, 0.f);
  ((float4*)out)[idx] = o;
}

extern "C" void kernel_launch(void* const* d_in, const int* in_sizes, int n_in,
                              void* d_out, int out_size, void* d_ws, size_t ws_size,
                              hipStream_t stream) {
  (void)in_sizes; (void)n_in; (void)out_size; (void)ws_size;
  const float* emb = (const float*)d_in[0];
  const int* adj = (const int*)d_in[1];
  const float* W = (const float*)d_in[2];
  const float* a = (const float*)d_in[3];
  float* out = (float*)d_out;

  char* ws = (char*)d_ws;
  __bf16* Vt = (__bf16*)ws;                       // 3,145,728 B
  float* s = (float*)(ws + 3145728);              // 49,152 B
  float* t = (float*)(ws + 3194880);              // 49,152 B
  float* lpart = (float*)(ws + 3244032);          // 16*12288*4 = 786,432 B
  float* linv = (float*)(ws + 4030464);           // 49,152 B
  float* tmax = (float*)(ws + 4079616);           // 256 B
  float* part = (float*)(ws + 4079872);           // 16*12288*128*4 = 100,663,296 B

  k1_gemm<<<NN / 64, 256, 0, stream>>>(emb, W, a, Vt, s, t);
  ktmax<<<1, 256, 0, stream>>>(t, tmax);
  dim3 g2(NN / 128, CSPLIT);
  k2_attn<<<g2, 256, 0, stream>>>(adj, Vt, s, t, tmax, part, lpart);
  kl<<<NN / 256, 256, 0, stream>>>(lpart, linv);
  k3_fin<<<NN * DIM / 4 / 256, 256, 0, stream>>>(part, linv, out);
}

// Round 3
// 823.332 us; speedup vs baseline: 1.2277x; 1.2277x over previous
//
#include <hip/hip_runtime.h>

// GraphAttention: N=12288, IN=OUT=128.
// e_new = emb@W.T ; s = e_new@a1 ; t = e_new@a2
// e[i][j] = leaky(s_i + t_j) masked by adj; softmax rows; out = relu(att @ e_new)
//
//  k1: bf16 MFMA gemm emb@W.T -> Vt (bf16, transposed [d][j]), s[], t[] (fp32)
//  ktmax: Tmax = max_j t_j (fixed per-row softmax shift; softmax partials add)
//  k2: streaming masked-softmax-PV. adj + Vt staged through LDS with fully
//      COALESCED global loads (round-2 showed the scattered 16B A-fragment
//      loads saturate the vector-memory request pipe); A-fragment scatter
//      now reads LDS. Double-buffered chunks, 1 barrier/chunk, prefetch
//      issued before compute. 8 col-splits, partials to ws (no atomics).
//  kl: combine softmax-denominator partials -> 1/l per row
//  k3: out = relu( (sum of partials) * linv )

#define NN 12288
#define DIM 128
#define CSPLIT 8
#define COLS_PER (NN / CSPLIT)   // 1536
#define BK 32
#define NCHUNK (COLS_PER / BK)   // 48

typedef __bf16 bf16x8 __attribute__((ext_vector_type(8)));
typedef float f32x4 __attribute__((ext_vector_type(4)));

// ---------------- kernel 1: e_new = emb @ W.T (bf16 MFMA), emits Vt, s, t ----
__global__ __launch_bounds__(256) void k1_gemm(const float* __restrict__ emb,
                                               const float* __restrict__ W,
                                               const float* __restrict__ a,
                                               __bf16* __restrict__ Vt,
                                               float* __restrict__ s,
                                               float* __restrict__ t) {
  const int lane = threadIdx.x & 63;
  const int wave = threadIdx.x >> 6;
  const int m = lane & 15;
  const int quad = lane >> 4;
  const int row0 = blockIdx.x * 64 + wave * 16;  // this wave: 16 rows

  f32x4 acc[8];
#pragma unroll
  for (int nb = 0; nb < 8; nb++) acc[nb] = (f32x4){0.f, 0.f, 0.f, 0.f};

#pragma unroll
  for (int ks = 0; ks < 4; ks++) {
    const int k0 = ks * 32 + quad * 8;
    const float* ep = emb + (size_t)(row0 + m) * DIM + k0;
    float4 lo = *(const float4*)ep;
    float4 hi = *(const float4*)(ep + 4);
    bf16x8 af = {(__bf16)lo.x, (__bf16)lo.y, (__bf16)lo.z, (__bf16)lo.w,
                 (__bf16)hi.x, (__bf16)hi.y, (__bf16)hi.z, (__bf16)hi.w};
#pragma unroll
    for (int nb = 0; nb < 8; nb++) {
      const float* wp = W + (size_t)(nb * 16 + m) * DIM + k0;
      float4 wlo = *(const float4*)wp;
      float4 whi = *(const float4*)(wp + 4);
      bf16x8 bf = {(__bf16)wlo.x, (__bf16)wlo.y, (__bf16)wlo.z, (__bf16)wlo.w,
                   (__bf16)whi.x, (__bf16)whi.y, (__bf16)whi.z, (__bf16)whi.w};
      acc[nb] = __builtin_amdgcn_mfma_f32_16x16x32_bf16(af, bf, acc[nb], 0, 0, 0);
    }
  }

  float a1v[8], a2v[8];
#pragma unroll
  for (int nb = 0; nb < 8; nb++) {
    a1v[nb] = a[nb * 16 + m];
    a2v[nb] = a[DIM + nb * 16 + m];
  }
  // C/D layout: row = quad*4 + r, col = nb*16 + m
#pragma unroll
  for (int r = 0; r < 4; r++) {
    const int gr = row0 + quad * 4 + r;
    float ps = 0.f, pt = 0.f;
#pragma unroll
    for (int nb = 0; nb < 8; nb++) {
      float e = acc[nb][r];
      ps += e * a1v[nb];
      pt += e * a2v[nb];
      Vt[(size_t)(nb * 16 + m) * NN + gr] = (__bf16)e;
    }
    ps += __shfl_xor(ps, 1); ps += __shfl_xor(ps, 2);
    ps += __shfl_xor(ps, 4); ps += __shfl_xor(ps, 8);
    pt += __shfl_xor(pt, 1); pt += __shfl_xor(pt, 2);
    pt += __shfl_xor(pt, 4); pt += __shfl_xor(pt, 8);
    if (m == 0) { s[gr] = ps; t[gr] = pt; }
  }
}

// ---------------- kernel: Tmax = max(t) ------------------------------------
__global__ __launch_bounds__(256) void ktmax(const float* __restrict__ t,
                                             float* __restrict__ tmax) {
  __shared__ float red[256];
  float mx = -1e30f;
  for (int i = threadIdx.x; i < NN; i += 256) mx = fmaxf(mx, t[i]);
  red[threadIdx.x] = mx;
  __syncthreads();
  for (int off = 128; off; off >>= 1) {
    if ((int)threadIdx.x < off) red[threadIdx.x] = fmaxf(red[threadIdx.x], red[threadIdx.x + off]);
    __syncthreads();
  }
  if (threadIdx.x == 0) *tmax = red[0];
}

// ---------------- kernel 2: masked softmax + PV, LDS-staged -----------------
__global__ __launch_bounds__(256, 3) void k2_attn(const int* __restrict__ adj,
                                                  const __bf16* __restrict__ Vt,
                                                  const float* __restrict__ s,
                                                  const float* __restrict__ t,
                                                  const float* __restrict__ tmaxp,
                                                  float* __restrict__ part,
                                                  float* __restrict__ lpart) {
  // adj tile: 128 rows x 32 cols, 1 byte/elem, row stride 40 B (5 ulongs)
  __shared__ unsigned long long adjb[2][128][5];
  // Vt tile: 128 dims x 32 cols bf16, row stride 80 B (16B-aligned: 80=5*16)
  __shared__ __attribute__((aligned(16))) __bf16 vtb[2][128][40];

  const int tid = threadIdx.x;
  const int lane = tid & 63;
  const int wave = tid >> 6;
  const int m = lane & 15;
  const int quad = lane >> 4;
  const int row0 = blockIdx.x * 128;
  const int cs = blockIdx.y;
  const int col0 = cs * COLS_PER;
  const int rowA = row0 + wave * 32 + m;
  const int rowB = rowA + 16;

  const float Tmax = *tmaxp;
  const float sA = s[rowA], sB = s[rowB];
  const float uA = sA + Tmax, uB = sB + Tmax;
  const float mA = fmaxf(uA, 0.01f * uA);  // per-row fixed softmax shift (upper bound)
  const float mB = fmaxf(uB, 0.01f * uB);

  f32x4 accA[8], accB[8];
#pragma unroll
  for (int nb = 0; nb < 8; nb++) {
    accA[nb] = (f32x4){0.f, 0.f, 0.f, 0.f};
    accB[nb] = (f32x4){0.f, 0.f, 0.f, 0.f};
  }
  float lA = 0.f, lB = 0.f;

  // staging registers (global -> reg -> LDS)
  int4 ga[4];
  bf16x8 gv[2];
  const int fr = tid >> 3, fc = (tid & 7) * 4;  // adj: 8 rows x 128 B per inst
  const int vd = tid >> 2, vc = (tid & 3) * 8;  // Vt: 16 rows x 64 B per inst

  auto fetch = [&](int c) {
    const int cc = col0 + c * BK;
#pragma unroll
    for (int p = 0; p < 4; p++)
      ga[p] = *(const int4*)(adj + (size_t)(row0 + fr + p * 32) * NN + cc + fc);
#pragma unroll
    for (int p = 0; p < 2; p++)
      gv[p] = *(const bf16x8*)(Vt + (size_t)(vd + p * 64) * NN + cc + vc);
  };
  auto commit = [&](int b) {
#pragma unroll
    for (int p = 0; p < 4; p++) {
      unsigned pk = (unsigned)(ga[p].x != 0) | ((unsigned)(ga[p].y != 0) << 8) |
                    ((unsigned)(ga[p].z != 0) << 16) | ((unsigned)(ga[p].w != 0) << 24);
      *(unsigned*)((unsigned char*)&adjb[b][fr + p * 32][0] + fc) = pk;
    }
#pragma unroll
    for (int p = 0; p < 2; p++)
      *(bf16x8*)&vtb[b][vd + p * 64][vc] = gv[p];
  };

  fetch(0);
  commit(0);
  __syncthreads();

  for (int c = 0; c < NCHUNK; c++) {
    if (c + 1 < NCHUNK) fetch(c + 1);

    // ---- compute on buffer c&1 ----
    const int b = c & 1;
    const float* tp = t + col0 + c * BK + quad * 8;
    float4 ct0 = *(const float4*)tp;
    float4 ct1 = *(const float4*)(tp + 4);
    unsigned long long avA = adjb[b][wave * 32 + m][quad];
    unsigned long long avB = adjb[b][wave * 32 + 16 + m][quad];

    bf16x8 pA, pB;
#define PEL(frag, jj, tv, av, ss, mm, ll)                               \
    {                                                                   \
      float v = (ss) + (tv);                                            \
      float lv = fmaxf(v, 0.01f * v);                                   \
      float e = (((av) >> (8 * (jj))) & 1) ? __expf(lv - (mm)) : 0.f;   \
      (ll) += e;                                                        \
      frag[jj] = (__bf16)e;                                             \
    }
    PEL(pA, 0, ct0.x, avA, sA, mA, lA)
    PEL(pA, 1, ct0.y, avA, sA, mA, lA)
    PEL(pA, 2, ct0.z, avA, sA, mA, lA)
    PEL(pA, 3, ct0.w, avA, sA, mA, lA)
    PEL(pA, 4, ct1.x, avA, sA, mA, lA)
    PEL(pA, 5, ct1.y, avA, sA, mA, lA)
    PEL(pA, 6, ct1.z, avA, sA, mA, lA)
    PEL(pA, 7, ct1.w, avA, sA, mA, lA)
    PEL(pB, 0, ct0.x, avB, sB, mB, lB)
    PEL(pB, 1, ct0.y, avB, sB, mB, lB)
    PEL(pB, 2, ct0.z, avB, sB, mB, lB)
    PEL(pB, 3, ct0.w, avB, sB, mB, lB)
    PEL(pB, 4, ct1.x, avB, sB, mB, lB)
    PEL(pB, 5, ct1.y, avB, sB, mB, lB)
    PEL(pB, 6, ct1.z, avB, sB, mB, lB)
    PEL(pB, 7, ct1.w, avB, sB, mB, lB)
#undef PEL

#pragma unroll
    for (int nb = 0; nb < 8; nb++) {
      bf16x8 bv = *(const bf16x8*)&vtb[b][nb * 16 + m][quad * 8];
      accA[nb] = __builtin_amdgcn_mfma_f32_16x16x32_bf16(pA, bv, accA[nb], 0, 0, 0);
      accB[nb] = __builtin_amdgcn_mfma_f32_16x16x32_bf16(pB, bv, accB[nb], 0, 0, 0);
    }

    if (c + 1 < NCHUNK) commit((c + 1) & 1);
    __syncthreads();
  }

  // row-sum partials: lanes {m, m+16, m+32, m+48} hold same row
  lA += __shfl_xor(lA, 16); lA += __shfl_xor(lA, 32);
  lB += __shfl_xor(lB, 16); lB += __shfl_xor(lB, 32);
  if (quad == 0) {
    lpart[(size_t)cs * NN + rowA] = lA;
    lpart[(size_t)cs * NN + rowB] = lB;
  }

  // C/D layout: row = quad*4 + r, col = nb*16 + m. Plain stores to partial slice.
  float* po = part + ((size_t)cs * NN + row0 + wave * 32) * DIM;
#pragma unroll
  for (int nb = 0; nb < 8; nb++) {
#pragma unroll
    for (int r = 0; r < 4; r++) {
      po[(size_t)(quad * 4 + r) * DIM + nb * 16 + m] = accA[nb][r];
      po[(size_t)(16 + quad * 4 + r) * DIM + nb * 16 + m] = accB[nb][r];
    }
  }
}

// ---------------- kernel: combine denominator partials ----------------------
__global__ __launch_bounds__(256) void kl(const float* __restrict__ lpart,
                                          float* __restrict__ linv) {
  const int r = blockIdx.x * 256 + threadIdx.x;  // 48 blocks
  float l = 0.f;
#pragma unroll
  for (int cs = 0; cs < CSPLIT; cs++) l += lpart[(size_t)cs * NN + r];
  linv[r] = 1.0f / l;
}

// ---------------- kernel 3: reduce partials + normalize + relu ---------------
__global__ __launch_bounds__(256) void k3_fin(const float* __restrict__ part,
                                              const float* __restrict__ linv,
                                              float* __restrict__ out) {
  const int idx = blockIdx.x * 256 + threadIdx.x;  // over NN*DIM/4
  const int row = idx >> 5;                        // DIM/4 = 32 float4 per row
  const float4* p4 = (const float4*)part;
  float4 acc = p4[idx];
#pragma unroll
  for (int cs = 1; cs < CSPLIT; cs++) {
    float4 v = p4[(size_t)cs * (NN * DIM / 4) + idx];
    acc.x += v.x; acc.y += v.y; acc.z += v.z; acc.w += v.w;
  }
  const float li = linv[row];
  float4 o;
  o.x = fmaxf(acc.x * li, 0.f);
  o.y = fmaxf(acc.y * li, 0.f);
  o.z = fmaxf(acc.z * li, 0.f);
  o.w = fmaxf(acc.w * li, 0.f);
  ((float4*)out)[idx] = o;
}

extern "C" void kernel_launch(void* const* d_in, const int* in_sizes, int n_in,
                              void* d_out, int out_size, void* d_ws, size_t ws_size,
                              hipStream_t stream) {
  (void)in_sizes; (void)n_in; (void)out_size; (void)ws_size;
  const float* emb = (const float*)d_in[0];
  const int* adj = (const int*)d_in[1];
  const float* W = (const float*)d_in[2];
  const float* a = (const float*)d_in[3];
  float* out = (float*)d_out;

  char* ws = (char*)d_ws;
  __bf16* Vt = (__bf16*)ws;                       // 3,145,728 B
  float* s = (float*)(ws + 3145728);              // 49,152 B
  float* t = (float*)(ws + 3194880);              // 49,152 B
  float* lpart = (float*)(ws + 3244032);          // 8*12288*4 = 393,216 B
  float* linv = (float*)(ws + 3637248);           // 49,152 B
  float* tmax = (float*)(ws + 3686400);           // 256 B
  float* part = (float*)(ws + 3686656);           // 8*12288*128*4 = 50,331,648 B

  k1_gemm<<<NN / 64, 256, 0, stream>>>(emb, W, a, Vt, s, t);
  ktmax<<<1, 256, 0, stream>>>(t, tmax);
  dim3 g2(NN / 128, CSPLIT);
  k2_attn<<<g2, 256, 0, stream>>>(adj, Vt, s, t, tmax, part, lpart);
  kl<<<NN / 256, 256, 0, stream>>>(lpart, linv);
  k3_fin<<<NN * DIM / 4 / 256, 256, 0, stream>>>(part, linv, out);
}